// Round 1
// 688.920 us; speedup vs baseline: 1.6064x; 1.6064x over previous
//
#include <hip/hip_runtime.h>
#include <hip/hip_bf16.h>
#include <math.h>

#define B_     1024
#define VOCAB_ 130
#define EOS_   129

// Output FLOAT32 element offsets:
//   inv_features @0 (24576) | inv_class_emb @24576 (901120) | str_emb @925696
#define OUT_CLS_F  24576
#define OUT_STR_F  925696

// Workspace (float offsets): POOL 1024*32 | CNT 1024 | HC 1024*16 | T 2*128*48
#define OFF_POOL 0
#define OFF_CNT  32768
#define OFF_HC   33792
#define OFF_T    50176

static __device__ const int d_MAP[19] =
    {128,93,41,91,61,34,40,37,33,63,43,47,36,42,96,48,95,46,128};

__device__ __forceinline__ float sigm_(float x){
    return __builtin_amdgcn_rcpf(1.f + __builtin_amdgcn_exp2f(-1.4426950408889634f * x));
}
__device__ __forceinline__ float tanh_(float x){
    return 2.f * __builtin_amdgcn_rcpf(1.f + __builtin_amdgcn_exp2f(-2.8853900817779268f * x)) - 1.f;
}
__device__ __forceinline__ int badf(float v) {
    return (v != v) || (fabsf(v) > 1e30f);
}

// ---------------- k0: precompute gi tables T[dir][c][j] = Wih_j . emb[c] + bih[j] (+bhh[j] for j<32)
__global__ void k0_tables(const float* __restrict__ emb,
                          const float* __restrict__ WihF, const float* __restrict__ bihF,
                          const float* __restrict__ bhhF,
                          const float* __restrict__ WihB, const float* __restrict__ bihB,
                          const float* __restrict__ bhhB, float* ws)
{
    int i = blockIdx.x * 256 + threadIdx.x;
    if (i >= 12288) return;                 // 2 * 128 * 48
    int dir = i / 6144, r = i - dir * 6144;
    int c = r / 48, j = r - c * 48;
    const float* Wih = dir ? WihB : WihF;
    const float* bih = dir ? bihB : bihF;
    const float* bhh = dir ? bhhB : bhhF;
    float v = bih[j] + ((j < 32) ? bhh[j] : 0.f);
    if (c != 0) {                           // padding_idx=0 -> emb row 0 is zero
        const float* e = emb + c * 16;
        #pragma unroll
        for (int d = 0; d < 16; ++d) v = fmaf(Wih[j * 16 + d], e[d], v);
    }
    ws[OFF_T + i] = v;
}

// ---------------- k1: f32 gathers (str_emb with EOS, inv_class_emb), float4
__global__ void k1_embed(const int* oclass, const int* strs,
                         const float* emb, float* out)
{
    __shared__ __align__(16) float embF[VOCAB_ * 20];  // f32 rows, pitch 20
    __shared__ int chs[4 * 80];
    int bi = blockIdx.x, tid = threadIdx.x;

    for (int i = tid; i < VOCAB_ * 16; i += 256) {
        int r = i >> 4, c = i & 15;
        embF[r * 20 + c] = (r == 0) ? 0.f : emb[i];   // padding_idx=0
    }
    __syncthreads();

    if (bi < 14080) {
        int w = tid >> 6, lane = tid & 63;
        int s = bi * 4 + w;
        const int* cp = strs + (long)s * 80;
        int ca = cp[lane];
        int cb = (lane < 16) ? cp[64 + lane] : 0;
        // wave-parallel length via ballot (replaces 80-iter serial loop)
        unsigned long long m1 = __ballot(ca != 0);
        unsigned long long m2 = __ballot((lane < 16) && (cb != 0));
        int L = __popcll(m1) + __popcll(m2);
        if (lane == L) ca = EOS_;
        if (lane < 16 && (64 + lane) == L) cb = EOS_;
        chs[w * 80 + lane] = ca;                 // wave-local slice: no barrier needed
        if (lane < 16) chs[w * 80 + 64 + lane] = cb;
        float4* dst = (float4*)(out + OUT_STR_F + (long)s * 1280);
        #pragma unroll
        for (int it = 0; it < 5; ++it) {
            int q = it * 64 + lane;
            int row = q >> 2, part = q & 3;
            int ch = chs[w * 80 + row];
            dst[q] = *(const float4*)&embF[ch * 20 + part * 4];
        }
    } else {
        int q = (bi - 14080) * 256 + tid;
        int bs = q >> 2, part = q & 3;
        int c = d_MAP[oclass[bs]];
        float4* dst = (float4*)(out + OUT_CLS_F);
        dst[q] = *(const float4*)&embF[c * 20 + part * 4];
    }
}

// ---------------- k2: lane-parallel GRU (16 lanes per sequence, Whh in VGPRs)
// grid: [0,3520) fwd GRU | [3520,7040) bwd GRU | [7040,7104) class RNN
__global__ __launch_bounds__(256, 4) void k2_rnn(
    const int* oclass, const int* strs, const float* __restrict__ emb,
    const float* __restrict__ WhhF, const float* __restrict__ bhhF,
    const float* __restrict__ WhhB, const float* __restrict__ bhhB,
    const float* __restrict__ rWih, const float* __restrict__ rWhh,
    const float* __restrict__ rbih, const float* __restrict__ rbhh,
    float* ws)
{
    __shared__ __align__(16) float ldsT[128 * 52];   // 26624 B gi-table (pitch 52)
    __shared__ __align__(16) float ldsHB[256];       // per-group h exchange (16x16)
    int bi = blockIdx.x, tid = threadIdx.x;
    int grp = tid >> 4, j = tid & 15;
    float* hb = ldsHB + (grp << 4);

    if (bi < 7040) {
        bool fwd = bi < 3520;
        const float* __restrict__ Whh = fwd ? WhhF : WhhB;
        const float* __restrict__ bhh = fwd ? bhhF : bhhB;

        // load precomputed gi-table [128][48] -> LDS pitch 52 (float4)
        const float* Tg = ws + OFF_T + (fwd ? 0 : 6144);
        for (int i = tid; i < 1536; i += 256) {
            int c = i / 12, q = i - c * 12;
            *(float4*)&ldsT[c * 52 + q * 4] = *(const float4*)&Tg[i * 4];
        }

        // per-lane Whh rows for unit j (stay in VGPRs the whole kernel)
        float wr[16], wz[16], wn[16];
        #pragma unroll
        for (int k = 0; k < 4; ++k) {
            *(float4*)&wr[4 * k] = *(const float4*)&Whh[      j * 16 + 4 * k];
            *(float4*)&wz[4 * k] = *(const float4*)&Whh[256 + j * 16 + 4 * k];
            *(float4*)&wn[4 * k] = *(const float4*)&Whh[512 + j * 16 + 4 * k];
        }
        float bn = bhh[32 + j];
        __syncthreads();

        int s = (fwd ? bi : bi - 3520) * 16 + grp;
        const int* cp = strs + (long)s * 80;

        // group-parallel length: lane j counts positions j+16k (k=0..4), swizzle-reduce
        int cnt = 0;
        #pragma unroll
        for (int k = 0; k < 5; ++k) cnt += (cp[j + 16 * k] != 0);
        cnt += __builtin_amdgcn_ds_swizzle(cnt, (1 << 10) | 0x1f);
        cnt += __builtin_amdgcn_ds_swizzle(cnt, (2 << 10) | 0x1f);
        cnt += __builtin_amdgcn_ds_swizzle(cnt, (4 << 10) | 0x1f);
        cnt += __builtin_amdgcn_ds_swizzle(cnt, (8 << 10) | 0x1f);
        int L = cnt;

        float hj = 0.f;
        hb[j] = 0.f;
        if (L > 0) {
            int base = fwd ? 0 : (L - 1);
            int stp  = fwd ? 1 : -1;
            int c = cp[base];
            for (int t = 0; t < L; ++t) {
                int cn = (t + 1 < L) ? cp[base + (t + 1) * stp] : 0;   // prefetch
                const float* Trow = ldsT + c * 52 + j;
                float tr_ = Trow[0];
                float tz_ = Trow[16];
                float tn_ = Trow[32];
                float ar = 0.f, az = 0.f, an = bn;
                #pragma unroll
                for (int k = 0; k < 4; ++k) {
                    float4 h4 = *(const float4*)&hb[4 * k];
                    ar = fmaf(wr[4*k+0], h4.x, ar); az = fmaf(wz[4*k+0], h4.x, az); an = fmaf(wn[4*k+0], h4.x, an);
                    ar = fmaf(wr[4*k+1], h4.y, ar); az = fmaf(wz[4*k+1], h4.y, az); an = fmaf(wn[4*k+1], h4.y, an);
                    ar = fmaf(wr[4*k+2], h4.z, ar); az = fmaf(wz[4*k+2], h4.z, az); an = fmaf(wn[4*k+2], h4.z, an);
                    ar = fmaf(wr[4*k+3], h4.w, ar); az = fmaf(wz[4*k+3], h4.w, az); an = fmaf(wn[4*k+3], h4.w, an);
                }
                float rg = sigm_(tr_ + ar);
                float zg = sigm_(tz_ + az);
                float ng = tanh_(tn_ + rg * an);
                hj = zg * (hj - ng) + ng;          // (1-z)*n + z*h
                hb[j] = hj;                        // publish for next step
                __builtin_amdgcn_wave_barrier();   // pin write before next-iter reads
                c = cn;
            }
            int b = s / 55;
            atomicAdd(ws + OFF_POOL + b * 32 + (fwd ? 0 : 16) + j, hj);
            if (fwd && j == 0) atomicAdd(ws + OFF_CNT + b, 1.f);
        }
    } else {
        // ---- class RNN: 16 lanes per sample ----
        for (int i = tid; i < 19 * 16; i += 256) {
            int o = i >> 4, jj = i & 15;
            int c = d_MAP[o];
            float v = rbih[jj] + rbhh[jj];
            #pragma unroll
            for (int d = 0; d < 16; ++d)
                v = fmaf(rWih[jj * 16 + d], emb[c * 16 + d], v);
            ldsT[o * 20 + jj] = v;                 // T2, pitch 20
        }
        float wv[16];
        #pragma unroll
        for (int k = 0; k < 4; ++k)
            *(float4*)&wv[4 * k] = *(const float4*)&rWhh[j * 16 + 4 * k];
        __syncthreads();

        int smp = (bi - 7040) * 16 + grp;
        const int* op = oclass + (long)smp * 55;
        int cnt = 0;
        #pragma unroll
        for (int k = 0; k < 4; ++k) {
            int p = j + 16 * k;
            cnt += (p < 55 && op[p] != 18);
        }
        cnt += __builtin_amdgcn_ds_swizzle(cnt, (1 << 10) | 0x1f);
        cnt += __builtin_amdgcn_ds_swizzle(cnt, (2 << 10) | 0x1f);
        cnt += __builtin_amdgcn_ds_swizzle(cnt, (4 << 10) | 0x1f);
        cnt += __builtin_amdgcn_ds_swizzle(cnt, (8 << 10) | 0x1f);
        int len = cnt;

        float hj = 0.f;
        hb[j] = 0.f;
        if (len > 0) {
            int o = op[0];
            for (int t = 0; t < len; ++t) {
                int onx = (t + 1 < len) ? op[t + 1] : 0;
                float a = ldsT[o * 20 + j];
                #pragma unroll
                for (int k = 0; k < 4; ++k) {
                    float4 h4 = *(const float4*)&hb[4 * k];
                    a = fmaf(wv[4*k+0], h4.x, a);
                    a = fmaf(wv[4*k+1], h4.y, a);
                    a = fmaf(wv[4*k+2], h4.z, a);
                    a = fmaf(wv[4*k+3], h4.w, a);
                }
                hj = tanh_(a);
                hb[j] = hj;
                __builtin_amdgcn_wave_barrier();
                o = onx;
            }
        }
        ws[OFF_HC + smp * 16 + j] = hj;
    }
}

// ---------------- k3: fusion MLP (f32 in/out), conditional diagnostic
__global__ void k3_fuse(const float* fW1, const float* fb1,
                        const float* fW2, const float* fb2,
                        float* ws, float* out)
{
    int b = blockIdx.x * 256 + threadIdx.x;
    if (b >= B_) return;
    float inv = 1.f / (ws[OFF_CNT + b] + 1e-8f);
    float comb[48];
    #pragma unroll
    for (int j = 0; j < 16; ++j) comb[j] = ws[OFF_HC + b * 16 + j];
    #pragma unroll
    for (int j = 0; j < 32; ++j) comb[16 + j] = ws[OFF_POOL + b * 32 + j] * inv;

    float hid[16];
    #pragma unroll
    for (int o = 0; o < 16; ++o) {
        float v = fb1[o];
        #pragma unroll
        for (int i = 0; i < 48; ++i) v = fmaf(fW1[o * 48 + i], comb[i], v);
        hid[o] = v > 0.f ? v : 0.f;
    }
    #pragma unroll
    for (int o = 0; o < 24; ++o) {
        float v = fb2[o];
        #pragma unroll
        for (int i = 0; i < 16; ++i) v = fmaf(fW2[o * 16 + i], hid[i], v);
        out[b * 24 + o] = v;
    }

    if (b == 0) {   // silent on success
        int bb = 0;
        if (!badf(ws[OFF_POOL]))    bb |= 1;
        if (!badf(ws[OFF_HC]))      bb |= 2;
        if (ws[OFF_CNT] > 0.5f)     bb |= 4;
        if (bb != 7) {
            float code = 16384.f + 128.f * (float)bb;
            #pragma unroll
            for (int i = 4; i < 12; ++i) out[i] = code;
        }
    }
}

// ------------------------------------------------------------------- launch
extern "C" void kernel_launch(void* const* d_in, const int* in_sizes, int n_in,
                              void* d_out, int out_size, void* d_ws, size_t ws_size,
                              hipStream_t stream)
{
    const int*   oclass = (const int*)d_in[0];
    const int*   strs   = (const int*)d_in[1];
    const float* emb    = (const float*)d_in[2];
    const float* rWih   = (const float*)d_in[3];
    const float* rWhh   = (const float*)d_in[4];
    const float* rbih   = (const float*)d_in[5];
    const float* rbhh   = (const float*)d_in[6];
    const float* gWihF  = (const float*)d_in[7];
    const float* gWhhF  = (const float*)d_in[8];
    const float* gbihF  = (const float*)d_in[9];
    const float* gbhhF  = (const float*)d_in[10];
    const float* gWihB  = (const float*)d_in[11];
    const float* gWhhB  = (const float*)d_in[12];
    const float* gbihB  = (const float*)d_in[13];
    const float* gbhhB  = (const float*)d_in[14];
    const float* fW1    = (const float*)d_in[15];
    const float* fb1    = (const float*)d_in[16];
    const float* fW2    = (const float*)d_in[17];
    const float* fb2    = (const float*)d_in[18];

    float* ws  = (float*)d_ws;
    float* out = (float*)d_out;

    hipMemsetAsync(d_ws, 0, 33792 * sizeof(float), stream);

    k0_tables<<<48, 256, 0, stream>>>(emb, gWihF, gbihF, gbhhF,
                                      gWihB, gbihB, gbhhB, ws);
    k1_embed<<<14960, 256, 0, stream>>>(oclass, strs, emb, out);
    k2_rnn<<<7104, 256, 0, stream>>>(oclass, strs, emb,
                                     gWhhF, gbhhF, gWhhB, gbhhB,
                                     rWih, rWhh, rbih, rbhh, ws);
    k3_fuse<<<4, 256, 0, stream>>>(fW1, fb1, fW2, fb2, ws, out);
}

// Round 2
// 665.104 us; speedup vs baseline: 1.6639x; 1.0358x over previous
//
#include <hip/hip_runtime.h>
#include <hip/hip_bf16.h>
#include <math.h>

#define B_     1024
#define VOCAB_ 130
#define EOS_   129

// Output FLOAT32 element offsets:
//   inv_features @0 (24576) | inv_class_emb @24576 (901120) | str_emb @925696
#define OUT_CLS_F  24576
#define OUT_STR_F  925696

// Workspace (float offsets): POOL 1024*32 | CNT 1024 | HC 1024*16 | T 2*128*48
#define OFF_POOL 0
#define OFF_CNT  32768
#define OFF_HC   33792
#define OFF_T    50176

typedef float f2 __attribute__((ext_vector_type(2)));

static __device__ const int d_MAP[19] =
    {128,93,41,91,61,34,40,37,33,63,43,47,36,42,96,48,95,46,128};

__device__ __forceinline__ float sigm_(float x){
    return __builtin_amdgcn_rcpf(1.f + __builtin_amdgcn_exp2f(-1.4426950408889634f * x));
}
__device__ __forceinline__ float tanh_(float x){
    return 2.f * __builtin_amdgcn_rcpf(1.f + __builtin_amdgcn_exp2f(-2.8853900817779268f * x)) - 1.f;
}
__device__ __forceinline__ int badf(float v) {
    return (v != v) || (fabsf(v) > 1e30f);
}
__device__ __forceinline__ f2 mkf2(float a, float b){ f2 r; r.x = a; r.y = b; return r; }

// ---------------- k0: precompute gi tables T[dir][c][j] = Wih_j . emb[c] + bih[j] (+bhh[j] for j<32)
__global__ void k0_tables(const float* __restrict__ emb,
                          const float* __restrict__ WihF, const float* __restrict__ bihF,
                          const float* __restrict__ bhhF,
                          const float* __restrict__ WihB, const float* __restrict__ bihB,
                          const float* __restrict__ bhhB, float* ws)
{
    int i = blockIdx.x * 256 + threadIdx.x;
    if (i >= 12288) return;                 // 2 * 128 * 48
    int dir = i / 6144, r = i - dir * 6144;
    int c = r / 48, j = r - c * 48;
    const float* Wih = dir ? WihB : WihF;
    const float* bih = dir ? bihB : bihF;
    const float* bhh = dir ? bhhB : bhhF;
    float v = bih[j] + ((j < 32) ? bhh[j] : 0.f);
    if (c != 0) {                           // padding_idx=0 -> emb row 0 is zero
        const float* e = emb + c * 16;
        #pragma unroll
        for (int d = 0; d < 16; ++d) v = fmaf(Wih[j * 16 + d], e[d], v);
    }
    ws[OFF_T + i] = v;
}

// ---------------- k1: f32 gathers (str_emb with EOS, inv_class_emb), float4
__global__ void k1_embed(const int* oclass, const int* strs,
                         const float* emb, float* out)
{
    __shared__ __align__(16) float embF[VOCAB_ * 20];  // f32 rows, pitch 20
    __shared__ int chs[4 * 80];
    int bi = blockIdx.x, tid = threadIdx.x;

    for (int i = tid; i < VOCAB_ * 16; i += 256) {
        int r = i >> 4, c = i & 15;
        embF[r * 20 + c] = (r == 0) ? 0.f : emb[i];   // padding_idx=0
    }
    __syncthreads();

    if (bi < 14080) {
        int w = tid >> 6, lane = tid & 63;
        int s = bi * 4 + w;
        const int* cp = strs + (long)s * 80;
        int ca = cp[lane];
        int cb = (lane < 16) ? cp[64 + lane] : 0;
        // wave-parallel length via ballot
        unsigned long long m1 = __ballot(ca != 0);
        unsigned long long m2 = __ballot((lane < 16) && (cb != 0));
        int L = __popcll(m1) + __popcll(m2);
        if (lane == L) ca = EOS_;
        if (lane < 16 && (64 + lane) == L) cb = EOS_;
        chs[w * 80 + lane] = ca;                 // wave-local slice: no barrier needed
        if (lane < 16) chs[w * 80 + 64 + lane] = cb;
        float4* dst = (float4*)(out + OUT_STR_F + (long)s * 1280);
        #pragma unroll
        for (int it = 0; it < 5; ++it) {
            int q = it * 64 + lane;
            int row = q >> 2, part = q & 3;
            int ch = chs[w * 80 + row];
            dst[q] = *(const float4*)&embF[ch * 20 + part * 4];
        }
    } else {
        int q = (bi - 14080) * 256 + tid;
        int bs = q >> 2, part = q & 3;
        int c = d_MAP[oclass[bs]];
        float4* dst = (float4*)(out + OUT_CLS_F);
        dst[q] = *(const float4*)&embF[c * 20 + part * 4];
    }
}

// ---------------- k2: lane-parallel GRU (16 lanes per sequence, Whh in VGPRs, pk_fma)
// grid: [0,3520) fwd GRU | [3520,7040) bwd GRU | [7040,7104) class RNN
__global__ __launch_bounds__(256, 3) void k2_rnn(
    const int* oclass, const int* strs, const float* __restrict__ emb,
    const float* __restrict__ WhhF, const float* __restrict__ bhhF,
    const float* __restrict__ WhhB, const float* __restrict__ bhhB,
    const float* __restrict__ rWih, const float* __restrict__ rWhh,
    const float* __restrict__ rbih, const float* __restrict__ rbhh,
    float* ws)
{
    __shared__ float ldsT[128 * 49];                 // 25088 B gi-table (pitch 49, bank stride 17)
    __shared__ __align__(16) float ldsHB[256];       // per-group h exchange (16x16)
    int bi = blockIdx.x, tid = threadIdx.x;
    int grp = tid >> 4, j = tid & 15;
    float* hb = ldsHB + (grp << 4);

    if (bi < 7040) {
        bool fwd = bi < 3520;
        const float* __restrict__ Whh = fwd ? WhhF : WhhB;
        const float* __restrict__ bhh = fwd ? bhhF : bhhB;

        // load precomputed gi-table [128][48] -> LDS pitch 49 (scalar, one-time)
        const float* Tg = ws + OFF_T + (fwd ? 0 : 6144);
        for (int i = tid; i < 6144; i += 256) {
            int c = i / 48, q = i - c * 48;
            ldsT[c * 49 + q] = Tg[i];
        }

        // per-lane Whh rows for unit j, as float2 pairs (pk_fma operands)
        f2 wr[8], wz[8], wn[8];
        #pragma unroll
        for (int k = 0; k < 4; ++k) {
            float4 a = *(const float4*)&Whh[      j * 16 + 4 * k];
            float4 b = *(const float4*)&Whh[256 + j * 16 + 4 * k];
            float4 c4 = *(const float4*)&Whh[512 + j * 16 + 4 * k];
            wr[2*k] = mkf2(a.x, a.y);  wr[2*k+1] = mkf2(a.z, a.w);
            wz[2*k] = mkf2(b.x, b.y);  wz[2*k+1] = mkf2(b.z, b.w);
            wn[2*k] = mkf2(c4.x, c4.y); wn[2*k+1] = mkf2(c4.z, c4.w);
        }
        float bn = bhh[32 + j];
        __syncthreads();

        int s = (fwd ? bi : bi - 3520) * 16 + grp;
        const int* cp = strs + (long)s * 80;

        // group-parallel length: lane j counts positions j+16k, swizzle-reduce
        int cnt = 0;
        #pragma unroll
        for (int k = 0; k < 5; ++k) cnt += (cp[j + 16 * k] != 0);
        cnt += __builtin_amdgcn_ds_swizzle(cnt, (1 << 10) | 0x1f);
        cnt += __builtin_amdgcn_ds_swizzle(cnt, (2 << 10) | 0x1f);
        cnt += __builtin_amdgcn_ds_swizzle(cnt, (4 << 10) | 0x1f);
        cnt += __builtin_amdgcn_ds_swizzle(cnt, (8 << 10) | 0x1f);
        int L = cnt;

        float hj = 0.f;
        hb[j] = 0.f;
        if (L > 0) {
            int base = fwd ? 0 : (L - 1);
            int stp  = fwd ? 1 : -1;
            int c = cp[base];
            for (int t = 0; t < L; ++t) {
                int cn = (t + 1 < L) ? cp[base + (t + 1) * stp] : 0;   // prefetch
                const float* Trow = ldsT + c * 49;
                float tr_ = Trow[j];
                float tz_ = Trow[16 + j];
                float tn_ = Trow[32 + j];
                f2 ar = mkf2(0.f, 0.f), az = mkf2(0.f, 0.f), an = mkf2(0.f, 0.f);
                #pragma unroll
                for (int k = 0; k < 4; ++k) {
                    float4 h4 = *(const float4*)&hb[4 * k];
                    f2 h0 = mkf2(h4.x, h4.y), h1 = mkf2(h4.z, h4.w);
                    ar = __builtin_elementwise_fma(wr[2*k],   h0, ar);
                    az = __builtin_elementwise_fma(wz[2*k],   h0, az);
                    an = __builtin_elementwise_fma(wn[2*k],   h0, an);
                    ar = __builtin_elementwise_fma(wr[2*k+1], h1, ar);
                    az = __builtin_elementwise_fma(wz[2*k+1], h1, az);
                    an = __builtin_elementwise_fma(wn[2*k+1], h1, an);
                }
                float rg = sigm_(tr_ + ar.x + ar.y);
                float zg = sigm_(tz_ + az.x + az.y);
                float ng = tanh_(tn_ + rg * (bn + an.x + an.y));
                hj = zg * (hj - ng) + ng;          // (1-z)*n + z*h
                hb[j] = hj;                        // publish for next step
                __builtin_amdgcn_wave_barrier();   // pin write before next-iter reads
                c = cn;
            }
            int b = s / 55;
            atomicAdd(ws + OFF_POOL + b * 32 + (fwd ? 0 : 16) + j, hj);
            if (fwd && j == 0) atomicAdd(ws + OFF_CNT + b, 1.f);
        }
    } else {
        // ---- class RNN: 16 lanes per sample ----
        for (int i = tid; i < 19 * 16; i += 256) {
            int o = i >> 4, jj = i & 15;
            int c = d_MAP[o];
            float v = rbih[jj] + rbhh[jj];
            #pragma unroll
            for (int d = 0; d < 16; ++d)
                v = fmaf(rWih[jj * 16 + d], emb[c * 16 + d], v);
            ldsT[o * 20 + jj] = v;                 // T2, pitch 20
        }
        f2 wv[8];
        #pragma unroll
        for (int k = 0; k < 4; ++k) {
            float4 a = *(const float4*)&rWhh[j * 16 + 4 * k];
            wv[2*k] = mkf2(a.x, a.y);  wv[2*k+1] = mkf2(a.z, a.w);
        }
        __syncthreads();

        int smp = (bi - 7040) * 16 + grp;
        const int* op = oclass + (long)smp * 55;
        int cnt = 0;
        #pragma unroll
        for (int k = 0; k < 4; ++k) {
            int p = j + 16 * k;
            cnt += (p < 55 && op[p] != 18);
        }
        cnt += __builtin_amdgcn_ds_swizzle(cnt, (1 << 10) | 0x1f);
        cnt += __builtin_amdgcn_ds_swizzle(cnt, (2 << 10) | 0x1f);
        cnt += __builtin_amdgcn_ds_swizzle(cnt, (4 << 10) | 0x1f);
        cnt += __builtin_amdgcn_ds_swizzle(cnt, (8 << 10) | 0x1f);
        int len = cnt;

        float hj = 0.f;
        hb[j] = 0.f;
        if (len > 0) {
            int o = op[0];
            for (int t = 0; t < len; ++t) {
                int onx = (t + 1 < len) ? op[t + 1] : 0;
                float a = ldsT[o * 20 + j];
                f2 a2 = mkf2(0.f, 0.f);
                #pragma unroll
                for (int k = 0; k < 4; ++k) {
                    float4 h4 = *(const float4*)&hb[4 * k];
                    a2 = __builtin_elementwise_fma(wv[2*k],   mkf2(h4.x, h4.y), a2);
                    a2 = __builtin_elementwise_fma(wv[2*k+1], mkf2(h4.z, h4.w), a2);
                }
                hj = tanh_(a + a2.x + a2.y);
                hb[j] = hj;
                __builtin_amdgcn_wave_barrier();
                o = onx;
            }
        }
        ws[OFF_HC + smp * 16 + j] = hj;
    }
}

// ---------------- k3: fusion MLP (f32 in/out), conditional diagnostic
__global__ void k3_fuse(const float* fW1, const float* fb1,
                        const float* fW2, const float* fb2,
                        float* ws, float* out)
{
    int b = blockIdx.x * 256 + threadIdx.x;
    if (b >= B_) return;
    float inv = 1.f / (ws[OFF_CNT + b] + 1e-8f);
    float comb[48];
    #pragma unroll
    for (int j = 0; j < 16; ++j) comb[j] = ws[OFF_HC + b * 16 + j];
    #pragma unroll
    for (int j = 0; j < 32; ++j) comb[16 + j] = ws[OFF_POOL + b * 32 + j] * inv;

    float hid[16];
    #pragma unroll
    for (int o = 0; o < 16; ++o) {
        float v = fb1[o];
        #pragma unroll
        for (int i = 0; i < 48; ++i) v = fmaf(fW1[o * 48 + i], comb[i], v);
        hid[o] = v > 0.f ? v : 0.f;
    }
    #pragma unroll
    for (int o = 0; o < 24; ++o) {
        float v = fb2[o];
        #pragma unroll
        for (int i = 0; i < 16; ++i) v = fmaf(fW2[o * 16 + i], hid[i], v);
        out[b * 24 + o] = v;
    }

    if (b == 0) {   // silent on success
        int bb = 0;
        if (!badf(ws[OFF_POOL]))    bb |= 1;
        if (!badf(ws[OFF_HC]))      bb |= 2;
        if (ws[OFF_CNT] > 0.5f)     bb |= 4;
        if (bb != 7) {
            float code = 16384.f + 128.f * (float)bb;
            #pragma unroll
            for (int i = 4; i < 12; ++i) out[i] = code;
        }
    }
}

// ------------------------------------------------------------------- launch
extern "C" void kernel_launch(void* const* d_in, const int* in_sizes, int n_in,
                              void* d_out, int out_size, void* d_ws, size_t ws_size,
                              hipStream_t stream)
{
    const int*   oclass = (const int*)d_in[0];
    const int*   strs   = (const int*)d_in[1];
    const float* emb    = (const float*)d_in[2];
    const float* rWih   = (const float*)d_in[3];
    const float* rWhh   = (const float*)d_in[4];
    const float* rbih   = (const float*)d_in[5];
    const float* rbhh   = (const float*)d_in[6];
    const float* gWihF  = (const float*)d_in[7];
    const float* gWhhF  = (const float*)d_in[8];
    const float* gbihF  = (const float*)d_in[9];
    const float* gbhhF  = (const float*)d_in[10];
    const float* gWihB  = (const float*)d_in[11];
    const float* gWhhB  = (const float*)d_in[12];
    const float* gbihB  = (const float*)d_in[13];
    const float* gbhhB  = (const float*)d_in[14];
    const float* fW1    = (const float*)d_in[15];
    const float* fb1    = (const float*)d_in[16];
    const float* fW2    = (const float*)d_in[17];
    const float* fb2    = (const float*)d_in[18];

    float* ws  = (float*)d_ws;
    float* out = (float*)d_out;

    hipMemsetAsync(d_ws, 0, 33792 * sizeof(float), stream);

    k0_tables<<<48, 256, 0, stream>>>(emb, gWihF, gbihF, gbhhF,
                                      gWihB, gbihB, gbhhB, ws);
    k1_embed<<<14960, 256, 0, stream>>>(oclass, strs, emb, out);
    k2_rnn<<<7104, 256, 0, stream>>>(oclass, strs, emb,
                                     gWhhF, gbhhF, gWhhB, gbhhB,
                                     rWih, rWhh, rbih, rbhh, ws);
    k3_fuse<<<4, 256, 0, stream>>>(fW1, fb1, fW2, fb2, ws, out);
}

// Round 3
// 646.609 us; speedup vs baseline: 1.7115x; 1.0286x over previous
//
#include <hip/hip_runtime.h>
#include <hip/hip_bf16.h>
#include <math.h>

#define B_     1024
#define VOCAB_ 130
#define EOS_   129

// Output FLOAT32 element offsets:
//   inv_features @0 (24576) | inv_class_emb @24576 (901120) | str_emb @925696
#define OUT_CLS_F  24576
#define OUT_STR_F  925696

// Workspace (float offsets): POOL 1024*32 | CNT 1024 | HC 1024*16 | T 2*128*48
#define OFF_POOL 0
#define OFF_CNT  32768
#define OFF_HC   33792
#define OFF_T    50176

// merged-grid geometry: 7104 k2-role blocks interleaved 1:2 with 14960 k1-role
#define NK2      7104
#define NK1      14960
#define NINT     21312          // 3 * NK2: interleaved prefix
#define NTOT     22064

typedef float f2 __attribute__((ext_vector_type(2)));

static __device__ const int d_MAP[19] =
    {128,93,41,91,61,34,40,37,33,63,43,47,36,42,96,48,95,46,128};

__device__ __forceinline__ float sigm_(float x){
    return __builtin_amdgcn_rcpf(1.f + __builtin_amdgcn_exp2f(-1.4426950408889634f * x));
}
__device__ __forceinline__ float tanh_(float x){
    return 2.f * __builtin_amdgcn_rcpf(1.f + __builtin_amdgcn_exp2f(-2.8853900817779268f * x)) - 1.f;
}
__device__ __forceinline__ int badf(float v) {
    return (v != v) || (fabsf(v) > 1e30f);
}
__device__ __forceinline__ f2 mkf2(float a, float b){ f2 r; r.x = a; r.y = b; return r; }

// ---------------- k0: precompute gi tables T[dir][c][j] = Wih_j . emb[c] + bih[j] (+bhh[j] for j<32)
__global__ void k0_tables(const float* __restrict__ emb,
                          const float* __restrict__ WihF, const float* __restrict__ bihF,
                          const float* __restrict__ bhhF,
                          const float* __restrict__ WihB, const float* __restrict__ bihB,
                          const float* __restrict__ bhhB, float* ws)
{
    int i = blockIdx.x * 256 + threadIdx.x;
    if (i >= 12288) return;                 // 2 * 128 * 48
    int dir = i / 6144, r = i - dir * 6144;
    int c = r / 48, j = r - c * 48;
    const float* Wih = dir ? WihB : WihF;
    const float* bih = dir ? bihB : bihF;
    const float* bhh = dir ? bhhB : bhhF;
    float v = bih[j] + ((j < 32) ? bhh[j] : 0.f);
    if (c != 0) {                           // padding_idx=0 -> emb row 0 is zero
        const float* e = emb + c * 16;
        #pragma unroll
        for (int d = 0; d < 16; ++d) v = fmaf(Wih[j * 16 + d], e[d], v);
    }
    ws[OFF_T + i] = v;
}

// ---------------- k12: merged embed-gather (k1 role) + GRU/RNN (k2 role)
// role by block index: bi<21312: bi%3==0 -> k2(bi/3), else k1(bi - bi/3 - 1);
//                      bi>=21312: k1(14208 + bi - 21312)
// LDS overlay: k2 uses [0,6272) T-table(pitch49) + [6272,6528) h-exchange
//              k1 uses [0,2600) embF(pitch20)   + [2600,2920) chs
__global__ __launch_bounds__(256)
__attribute__((amdgpu_waves_per_eu(1, 4)))
void k12_main(const int* oclass, const int* strs, const float* __restrict__ emb,
              const float* __restrict__ WhhF, const float* __restrict__ bhhF,
              const float* __restrict__ WhhB, const float* __restrict__ bhhB,
              const float* __restrict__ rWih, const float* __restrict__ rWhh,
              const float* __restrict__ rbih, const float* __restrict__ rbhh,
              float* ws, float* out)
{
    __shared__ __align__(16) float smem[6528];       // 26112 B union
    int bi0 = blockIdx.x, tid = threadIdx.x;

    int k2id = -1, k1id;
    if (bi0 < NINT) {
        if (bi0 % 3 == 0) k2id = bi0 / 3;
        else              k1id = bi0 - bi0 / 3 - 1;
    } else {
        k1id = 14208 + (bi0 - NINT);
    }

    if (k2id < 0) {
        // ================= k1 role: f32 gathers (str_emb + EOS, inv_class_emb)
        float* embF = smem;                          // pitch 20
        int*   chs  = (int*)(smem + 2600);           // 4 * 80
        for (int i = tid; i < VOCAB_ * 16; i += 256) {
            int r = i >> 4, c = i & 15;
            embF[r * 20 + c] = (r == 0) ? 0.f : emb[i];   // padding_idx=0
        }
        __syncthreads();

        if (k1id < 14080) {
            int w = tid >> 6, lane = tid & 63;
            int s = k1id * 4 + w;
            const int* cp = strs + (long)s * 80;
            int ca = cp[lane];
            int cb = (lane < 16) ? cp[64 + lane] : 0;
            unsigned long long m1 = __ballot(ca != 0);
            unsigned long long m2 = __ballot((lane < 16) && (cb != 0));
            int L = __popcll(m1) + __popcll(m2);
            if (lane == L) ca = EOS_;
            if (lane < 16 && (64 + lane) == L) cb = EOS_;
            chs[w * 80 + lane] = ca;                 // wave-local slice: no barrier
            if (lane < 16) chs[w * 80 + 64 + lane] = cb;
            float4* dst = (float4*)(out + OUT_STR_F + (long)s * 1280);
            #pragma unroll
            for (int it = 0; it < 5; ++it) {
                int q = it * 64 + lane;
                int row = q >> 2, part = q & 3;
                int ch = chs[w * 80 + row];
                dst[q] = *(const float4*)&embF[ch * 20 + part * 4];
            }
        } else {
            int q = (k1id - 14080) * 256 + tid;
            int bs = q >> 2, part = q & 3;
            int c = d_MAP[oclass[bs]];
            float4* dst = (float4*)(out + OUT_CLS_F);
            dst[q] = *(const float4*)&embF[c * 20 + part * 4];
        }
        return;
    }

    // ================= k2 role: lane-parallel GRU / class RNN
    float* ldsT  = smem;                             // pitch 49 gi-table
    float* ldsHB = smem + 6272;                      // 16 groups x 16
    int bi = k2id;
    int grp = tid >> 4, j = tid & 15;
    float* hb = ldsHB + (grp << 4);

    if (bi < 7040) {
        bool fwd = bi < 3520;
        const float* __restrict__ Whh = fwd ? WhhF : WhhB;
        const float* __restrict__ bhh = fwd ? bhhF : bhhB;

        // load precomputed gi-table [128][48] -> LDS pitch 49
        const float* Tg = ws + OFF_T + (fwd ? 0 : 6144);
        for (int i = tid; i < 6144; i += 256) {
            int c = i / 48, q = i - c * 48;
            ldsT[c * 49 + q] = Tg[i];
        }

        // per-lane Whh rows for unit j, as float2 pairs (pk_fma operands)
        f2 wr[8], wz[8], wn[8];
        #pragma unroll
        for (int k = 0; k < 4; ++k) {
            float4 a = *(const float4*)&Whh[      j * 16 + 4 * k];
            float4 b = *(const float4*)&Whh[256 + j * 16 + 4 * k];
            float4 c4 = *(const float4*)&Whh[512 + j * 16 + 4 * k];
            wr[2*k] = mkf2(a.x, a.y);  wr[2*k+1] = mkf2(a.z, a.w);
            wz[2*k] = mkf2(b.x, b.y);  wz[2*k+1] = mkf2(b.z, b.w);
            wn[2*k] = mkf2(c4.x, c4.y); wn[2*k+1] = mkf2(c4.z, c4.w);
        }
        float bn = bhh[32 + j];
        // pin the 24 weight pairs into arch VGPRs (blocks AGPR demotion/remat)
        #pragma unroll
        for (int k = 0; k < 8; ++k) {
            asm volatile("" : "+v"(wr[k]));
            asm volatile("" : "+v"(wz[k]));
            asm volatile("" : "+v"(wn[k]));
        }
        __syncthreads();

        int s = (fwd ? bi : bi - 3520) * 16 + grp;
        const int* cp = strs + (long)s * 80;

        int cnt = 0;
        #pragma unroll
        for (int k = 0; k < 5; ++k) cnt += (cp[j + 16 * k] != 0);
        cnt += __builtin_amdgcn_ds_swizzle(cnt, (1 << 10) | 0x1f);
        cnt += __builtin_amdgcn_ds_swizzle(cnt, (2 << 10) | 0x1f);
        cnt += __builtin_amdgcn_ds_swizzle(cnt, (4 << 10) | 0x1f);
        cnt += __builtin_amdgcn_ds_swizzle(cnt, (8 << 10) | 0x1f);
        int L = cnt;

        float hj = 0.f;
        hb[j] = 0.f;
        if (L > 0) {
            int base = fwd ? 0 : (L - 1);
            int stp  = fwd ? 1 : -1;
            int c = cp[base];
            for (int t = 0; t < L; ++t) {
                int cn = (t + 1 < L) ? cp[base + (t + 1) * stp] : 0;   // prefetch
                const float* Trow = ldsT + c * 49;
                f2 ar = mkf2(Trow[j], 0.f);
                f2 az = mkf2(Trow[16 + j], 0.f);
                f2 an = mkf2(bn, 0.f);
                float tn_ = Trow[32 + j];
                #pragma unroll
                for (int k = 0; k < 4; ++k) {
                    float4 h4 = *(const float4*)&hb[4 * k];
                    f2 h0 = mkf2(h4.x, h4.y), h1 = mkf2(h4.z, h4.w);
                    ar = __builtin_elementwise_fma(wr[2*k],   h0, ar);
                    az = __builtin_elementwise_fma(wz[2*k],   h0, az);
                    an = __builtin_elementwise_fma(wn[2*k],   h0, an);
                    ar = __builtin_elementwise_fma(wr[2*k+1], h1, ar);
                    az = __builtin_elementwise_fma(wz[2*k+1], h1, az);
                    an = __builtin_elementwise_fma(wn[2*k+1], h1, an);
                }
                float rg = sigm_(ar.x + ar.y);
                float zg = sigm_(az.x + az.y);
                float ng = tanh_(fmaf(rg, an.x + an.y, tn_));
                hj = fmaf(zg, hj - ng, ng);        // (1-z)*n + z*h
                hb[j] = hj;                        // publish for next step
                __builtin_amdgcn_wave_barrier();   // pin write before next-iter reads
                c = cn;
            }
            int b = s / 55;
            atomicAdd(ws + OFF_POOL + b * 32 + (fwd ? 0 : 16) + j, hj);
            if (fwd && j == 0) atomicAdd(ws + OFF_CNT + b, 1.f);
        }
    } else {
        // ---- class RNN: 16 lanes per sample ----
        for (int i = tid; i < 19 * 16; i += 256) {
            int o = i >> 4, jj = i & 15;
            int c = d_MAP[o];
            float v = rbih[jj] + rbhh[jj];
            #pragma unroll
            for (int d = 0; d < 16; ++d)
                v = fmaf(rWih[jj * 16 + d], emb[c * 16 + d], v);
            ldsT[o * 20 + jj] = v;                 // T2, pitch 20
        }
        f2 wv[8];
        #pragma unroll
        for (int k = 0; k < 4; ++k) {
            float4 a = *(const float4*)&rWhh[j * 16 + 4 * k];
            wv[2*k] = mkf2(a.x, a.y);  wv[2*k+1] = mkf2(a.z, a.w);
        }
        __syncthreads();

        int smp = (bi - 7040) * 16 + grp;
        const int* op = oclass + (long)smp * 55;
        int cnt = 0;
        #pragma unroll
        for (int k = 0; k < 4; ++k) {
            int p = j + 16 * k;
            cnt += (p < 55 && op[p] != 18);
        }
        cnt += __builtin_amdgcn_ds_swizzle(cnt, (1 << 10) | 0x1f);
        cnt += __builtin_amdgcn_ds_swizzle(cnt, (2 << 10) | 0x1f);
        cnt += __builtin_amdgcn_ds_swizzle(cnt, (4 << 10) | 0x1f);
        cnt += __builtin_amdgcn_ds_swizzle(cnt, (8 << 10) | 0x1f);
        int len = cnt;

        float hj = 0.f;
        hb[j] = 0.f;
        if (len > 0) {
            int o = op[0];
            for (int t = 0; t < len; ++t) {
                int onx = (t + 1 < len) ? op[t + 1] : 0;
                f2 a2 = mkf2(ldsT[o * 20 + j], 0.f);
                #pragma unroll
                for (int k = 0; k < 4; ++k) {
                    float4 h4 = *(const float4*)&hb[4 * k];
                    a2 = __builtin_elementwise_fma(wv[2*k],   mkf2(h4.x, h4.y), a2);
                    a2 = __builtin_elementwise_fma(wv[2*k+1], mkf2(h4.z, h4.w), a2);
                }
                hj = tanh_(a2.x + a2.y);
                hb[j] = hj;
                __builtin_amdgcn_wave_barrier();
                o = onx;
            }
        }
        ws[OFF_HC + smp * 16 + j] = hj;
    }
}

// ---------------- k3: fusion MLP (f32 in/out), conditional diagnostic
__global__ void k3_fuse(const float* fW1, const float* fb1,
                        const float* fW2, const float* fb2,
                        float* ws, float* out)
{
    int b = blockIdx.x * 256 + threadIdx.x;
    if (b >= B_) return;
    float inv = 1.f / (ws[OFF_CNT + b] + 1e-8f);
    float comb[48];
    #pragma unroll
    for (int j = 0; j < 16; ++j) comb[j] = ws[OFF_HC + b * 16 + j];
    #pragma unroll
    for (int j = 0; j < 32; ++j) comb[16 + j] = ws[OFF_POOL + b * 32 + j] * inv;

    float hid[16];
    #pragma unroll
    for (int o = 0; o < 16; ++o) {
        float v = fb1[o];
        #pragma unroll
        for (int i = 0; i < 48; ++i) v = fmaf(fW1[o * 48 + i], comb[i], v);
        hid[o] = v > 0.f ? v : 0.f;
    }
    #pragma unroll
    for (int o = 0; o < 24; ++o) {
        float v = fb2[o];
        #pragma unroll
        for (int i = 0; i < 16; ++i) v = fmaf(fW2[o * 16 + i], hid[i], v);
        out[b * 24 + o] = v;
    }

    if (b == 0) {   // silent on success
        int bb = 0;
        if (!badf(ws[OFF_POOL]))    bb |= 1;
        if (!badf(ws[OFF_HC]))      bb |= 2;
        if (ws[OFF_CNT] > 0.5f)     bb |= 4;
        if (bb != 7) {
            float code = 16384.f + 128.f * (float)bb;
            #pragma unroll
            for (int i = 4; i < 12; ++i) out[i] = code;
        }
    }
}

// ------------------------------------------------------------------- launch
extern "C" void kernel_launch(void* const* d_in, const int* in_sizes, int n_in,
                              void* d_out, int out_size, void* d_ws, size_t ws_size,
                              hipStream_t stream)
{
    const int*   oclass = (const int*)d_in[0];
    const int*   strs   = (const int*)d_in[1];
    const float* emb    = (const float*)d_in[2];
    const float* rWih   = (const float*)d_in[3];
    const float* rWhh   = (const float*)d_in[4];
    const float* rbih   = (const float*)d_in[5];
    const float* rbhh   = (const float*)d_in[6];
    const float* gWihF  = (const float*)d_in[7];
    const float* gWhhF  = (const float*)d_in[8];
    const float* gbihF  = (const float*)d_in[9];
    const float* gbhhF  = (const float*)d_in[10];
    const float* gWihB  = (const float*)d_in[11];
    const float* gWhhB  = (const float*)d_in[12];
    const float* gbihB  = (const float*)d_in[13];
    const float* gbhhB  = (const float*)d_in[14];
    const float* fW1    = (const float*)d_in[15];
    const float* fb1    = (const float*)d_in[16];
    const float* fW2    = (const float*)d_in[17];
    const float* fb2    = (const float*)d_in[18];

    float* ws  = (float*)d_ws;
    float* out = (float*)d_out;

    hipMemsetAsync(d_ws, 0, 33792 * sizeof(float), stream);

    k0_tables<<<48, 256, 0, stream>>>(emb, gWihF, gbihF, gbhhF,
                                      gWihB, gbihB, gbhhB, ws);
    k12_main<<<NTOT, 256, 0, stream>>>(oclass, strs, emb,
                                       gWhhF, gbhhF, gWhhB, gbhhB,
                                       rWih, rWhh, rbih, rbhh, ws, out);
    k3_fuse<<<4, 256, 0, stream>>>(fW1, fb1, fW2, fb2, ws, out);
}